// Round 1
// baseline (579.284 us; speedup 1.0000x reference)
//
#include <hip/hip_runtime.h>
#include <hip/hip_bf16.h>

// LinearMPC: f = -2*einsum(Phi[:N],Q,dx); 100x PGD: u <- clip(u - 0.01*(H u + f))
// B=2048, M=512, N=64, NX=NU=8.
// Strategy: batch-partitioned persistent kernel. 128 blocks x 16 batch rows.
// u master fp32 in registers, u bf16 copy in LDS (MFMA A operand),
// H converted to bf16 in d_ws once, streamed from L2 as MFMA B operand.

typedef unsigned short ushort_t;
typedef __attribute__((ext_vector_type(8))) short short8;
typedef __attribute__((ext_vector_type(4))) float floatx4;

__device__ __forceinline__ unsigned short f32_to_bf16(float x) {
    unsigned int u = __builtin_bit_cast(unsigned int, x);
    u = (u + 0x7FFFu + ((u >> 16) & 1u)) >> 16;   // RNE
    return (unsigned short)u;
}

__global__ void convert_H_bf16(const float* __restrict__ H, ushort_t* __restrict__ Hb) {
    int idx = blockIdx.x * 256 + threadIdx.x;   // 1024 blocks x 256 = 262144
    Hb[idx] = f32_to_bf16(H[idx]);
}

// Block: 512 threads = 8 waves, 2 waves/SIMD. Each block owns 16 batch rows.
// Wave w owns output columns [w*64, w*64+64) as 4 MFMA n-tiles of 16.
__global__ __launch_bounds__(512, 2)
void pgd_kernel(const float* __restrict__ xref,      // [2048][65][8]
                const ushort_t* __restrict__ Hb,     // [512][512] bf16
                const float* __restrict__ Phi,       // [65][8][8]
                const float* __restrict__ Q,         // [8][8]
                float* __restrict__ out)             // [2048][512]
{
    __shared__ __align__(16) ushort_t u_bf[16][520];   // +8 pad -> bank-conflict-free b128 reads
    __shared__ float W[64][64];                        // W[k][i*8+l] = sum_j Phi[k,i,j] Q[j,l]

    const int tid  = threadIdx.x;
    const int lane = tid & 63;
    const int w    = tid >> 6;        // wave 0..7
    const int quad = lane >> 4;       // 0..3
    const int lcol = lane & 15;       // 0..15
    const int b0   = blockIdx.x * 16;

    // ---- W = Phi[:64] @ Q  (4096 entries, 8 per thread) ----
    for (int e = tid; e < 4096; e += 512) {
        int k = e >> 6, i = (e >> 3) & 7, l = e & 7;
        float s = 0.f;
        #pragma unroll
        for (int j = 0; j < 8; ++j) s += Phi[k * 64 + i * 8 + j] * Q[j * 8 + l];
        W[k][i * 8 + l] = s;
    }
    // ---- zero u_bf (u0 = 0) ----
    for (int e = tid; e < 16 * 520; e += 512) ((ushort_t*)u_bf)[e] = 0;
    __syncthreads();

    // ---- f and u master, register-resident per lane in MFMA C/D layout ----
    // lane holds (m = quad*4+r, c = w*64 + t*16 + lcol) for t in 0..3, r in 0..3
    float f_reg[4][4];
    float u_reg[4][4];
    #pragma unroll
    for (int t = 0; t < 4; ++t) {
        int c = w * 64 + t * 16 + lcol;
        int k = c >> 3, i = c & 7;
        #pragma unroll
        for (int r = 0; r < 4; ++r) {
            int m = quad * 4 + r;
            const float* xr = xref + (long)(b0 + m) * 65 * 8;
            float s = 0.f;
            #pragma unroll
            for (int l = 0; l < 8; ++l)
                s += W[k][i * 8 + l] * (xr[k * 8 + l] - xr[l]);
            f_reg[t][r] = -2.0f * s;
            u_reg[t][r] = 0.0f;
        }
    }

    // ---- 100 PGD iterations ----
    for (int it = 0; it < 100; ++it) {
        floatx4 acc[4];
        #pragma unroll
        for (int t = 0; t < 4; ++t) acc[t] = (floatx4){0.f, 0.f, 0.f, 0.f};

        // grad tile [16 x 64 per wave] = u[16x512] @ H^T slice
        for (int ks = 0; ks < 16; ++ks) {
            int k0 = ks * 32 + quad * 8;
            short8 a = *(const short8*)&u_bf[lcol][k0];   // A[m=lcol][k0..k0+7]
            #pragma unroll
            for (int t = 0; t < 4; ++t) {
                int n = w * 64 + t * 16 + lcol;           // B[k][n]: row n of H, cols k0..k0+7
                short8 b = *(const short8*)&Hb[n * 512 + k0];
                acc[t] = __builtin_amdgcn_mfma_f32_16x16x32_bf16(a, b, acc[t], 0, 0, 0);
            }
        }
        __syncthreads();   // all waves done reading u_bf of iteration `it`
        #pragma unroll
        for (int t = 0; t < 4; ++t) {
            int c = w * 64 + t * 16 + lcol;
            #pragma unroll
            for (int r = 0; r < 4; ++r) {
                int m = quad * 4 + r;
                float g  = acc[t][r] + f_reg[t][r];
                float un = u_reg[t][r] - 0.01f * g;
                un = fminf(1.0f, fmaxf(-1.0f, un));
                u_reg[t][r] = un;
                u_bf[m][c]  = f32_to_bf16(un);
            }
        }
        __syncthreads();   // new u_bf visible to all waves
    }

    // ---- write final u (fp32) ----
    #pragma unroll
    for (int t = 0; t < 4; ++t) {
        int c = w * 64 + t * 16 + lcol;
        #pragma unroll
        for (int r = 0; r < 4; ++r) {
            int m = quad * 4 + r;
            out[(long)(b0 + m) * 512 + c] = u_reg[t][r];
        }
    }
}

extern "C" void kernel_launch(void* const* d_in, const int* in_sizes, int n_in,
                              void* d_out, int out_size, void* d_ws, size_t ws_size,
                              hipStream_t stream) {
    // inputs: 0=x0 (unused by reference), 1=xref, 2=H, 3=Phi, 4=Q
    const float* xref = (const float*)d_in[1];
    const float* H    = (const float*)d_in[2];
    const float* Phi  = (const float*)d_in[3];
    const float* Q    = (const float*)d_in[4];
    ushort_t* Hb = (ushort_t*)d_ws;            // 512*512*2 = 512 KB

    convert_H_bf16<<<1024, 256, 0, stream>>>(H, Hb);
    pgd_kernel<<<128, 512, 0, stream>>>(xref, Hb, Phi, Q, (float*)d_out);
}